// Round 5
// baseline (106.869 us; speedup 1.0000x reference)
//
#include <hip/hip_runtime.h>

#define EPS 1e-7f

// Native clang vector type, component-indexed only with constants after
// full unroll (SROA-friendly: no address-taking, no reinterpret of locals).
typedef float floatx4 __attribute__((ext_vector_type(4)));

// 8 consecutive samples per thread: d rows 8x6 = 12 float4, e rows 8x5 =
// 10 float4, out 10 float4. Plain stores (NOT nontemporal: nt at 80B/thread
// stride caused 2.6x write amplification in R4 — lines assembled from
// multiple store instructions must merge in L2).
__global__ __launch_bounds__(256) void attn_e_kernel(
    const float* __restrict__ dp, const float* __restrict__ ep,
    const float* __restrict__ Wp, const float* __restrict__ bp,
    float* __restrict__ out, int n8) // n8 = N/8
{
    int i = blockIdx.x * blockDim.x + threadIdx.x;
    if (i >= n8) return;

    float W = Wp[0];
    float bb[5];
    #pragma unroll
    for (int j = 0; j < 5; ++j) bb[j] = bp[j];

    const floatx4* d4 = (const floatx4*)dp;
    const floatx4* e4 = (const floatx4*)ep;

    floatx4 dv[12], ev[10], ov[10];
    #pragma unroll
    for (int k = 0; k < 12; ++k) dv[k] = d4[(size_t)i * 12 + k];
    #pragma unroll
    for (int k = 0; k < 10; ++k) ev[k] = e4[(size_t)i * 10 + k];

    #pragma unroll
    for (int r = 0; r < 8; ++r) {
        float s = 0.f;
        #pragma unroll
        for (int k = 0; k < 6; ++k) {
            int f = r * 6 + k;            // constant after unroll
            s += dv[f >> 2][f & 3];
        }
        float sw = s * W;

        float a[5];
        float asum = 0.f;
        #pragma unroll
        for (int j = 0; j < 5; ++j) {
            int f = r * 5 + j;
            float x = sw * ev[f >> 2][f & 3] + bb[j];
            // tanh(x) = 1 - 2/(exp(2x)+1); saturates correctly at +/-inf.
            float t = 1.f - 2.f / (__expf(2.f * x) + 1.f);
            float av = __expf(t);
            a[j] = av;
            asum += av;
        }
        float inv = 1.f / (asum + EPS);
        #pragma unroll
        for (int j = 0; j < 5; ++j) {
            int f = r * 5 + j;
            ov[f >> 2][f & 3] = ev[f >> 2][f & 3] * (a[j] * inv);
        }
    }

    floatx4* o4 = (floatx4*)out;
    #pragma unroll
    for (int k = 0; k < 10; ++k)
        o4[(size_t)i * 10 + k] = ov[k];
}

extern "C" void kernel_launch(void* const* d_in, const int* in_sizes, int n_in,
                              void* d_out, int out_size, void* d_ws, size_t ws_size,
                              hipStream_t stream) {
    const float* dp = (const float*)d_in[0]; // (N,6)
    const float* ep = (const float*)d_in[1]; // (N,5)
    const float* Wp = (const float*)d_in[2]; // (1,)
    const float* bp = (const float*)d_in[3]; // (5,)
    float* out = (float*)d_out;              // (N,5)

    int N = in_sizes[1] / 5; // e is N*5 elements
    int n8 = N / 8;          // N = 4194304 divisible by 8
    int threads = 256;
    int blocks = (n8 + threads - 1) / threads;
    attn_e_kernel<<<blocks, threads, 0, stream>>>(dp, ep, Wp, bp, out, n8);
}

// Round 6
// 59.917 us; speedup vs baseline: 1.7836x; 1.7836x over previous
//
#include <hip/hip_runtime.h>

#define EPS 1e-7f

typedef float floatx4 __attribute__((ext_vector_type(4)));

// Block = 256 threads owns 1024 contiguous samples.
// All global traffic is perfectly coalesced (lane-contiguous float4:
// 64-lane wave = one 1KB segment per instruction). AoS<->SoA conversion
// happens in LDS:
//   d: float4 loads -> partial row-sums via LDS atomicAdd into sT[1024]
//   e: float4 loads -> SoA scatter eT[5][1024] (bank = s%32, ~2-way worst)
//   compute: sample s = t + 256r -> stride-1 lane addressing, conflict-free
//   out: results overwrite eT in place -> SoA->AoS gather -> float4 stores
__global__ __launch_bounds__(256) void attn_e_kernel(
    const float* __restrict__ dp, const float* __restrict__ ep,
    const float* __restrict__ Wp, const float* __restrict__ bp,
    float* __restrict__ out)
{
    __shared__ float sT[1024];
    __shared__ float eT[5][1024];

    const int t = threadIdx.x;
    const size_t blk = blockIdx.x;

    const float W = Wp[0];
    const float b0 = bp[0], b1 = bp[1], b2 = bp[2], b3 = bp[3], b4 = bp[4];

    // zero row-sum accumulators (stride-1 lanes: conflict-free)
    #pragma unroll
    for (int r = 0; r < 4; ++r) sT[t + 256 * r] = 0.f;
    __syncthreads();

    // ---- stage d: 6 coalesced float4 loads -> row-sum partials (atomic)
    const floatx4* dp4 = (const floatx4*)dp;
    #pragma unroll
    for (int k = 0; k < 6; ++k) {
        floatx4 v = dp4[blk * 1536 + (size_t)(k * 256 + t)];
        int f0 = 1024 * k + 4 * t;      // float index within 6144-float tile
        int s0 = f0 / 6;
        int j0 = f0 % 6;                // 0, 2, or 4 (f0 is even)
        if (j0 <= 2) {                  // all 4 floats inside sample s0
            atomicAdd(&sT[s0], (v.x + v.y) + (v.z + v.w));
        } else {                        // j0==4: 2 floats in s0, 2 in s0+1
            atomicAdd(&sT[s0], v.x + v.y);
            atomicAdd(&sT[s0 + 1], v.z + v.w);
        }
    }

    // ---- stage e: 5 coalesced float4 loads -> SoA scatter
    const floatx4* ep4 = (const floatx4*)ep;
    #pragma unroll
    for (int k = 0; k < 5; ++k) {
        floatx4 v = ep4[blk * 1280 + (size_t)(k * 256 + t)];
        int f0 = 1024 * k + 4 * t;      // float index within 5120-float tile
        #pragma unroll
        for (int m = 0; m < 4; ++m) {
            int f = f0 + m;
            eT[f % 5][f / 5] = v[m];
        }
    }
    __syncthreads();

    // ---- compute: 4 samples per thread, strided s = t + 256r
    #pragma unroll
    for (int r = 0; r < 4; ++r) {
        int s = t + 256 * r;
        float sw = sT[s] * W;
        float e0 = eT[0][s], e1 = eT[1][s], e2 = eT[2][s],
              e3 = eT[3][s], e4 = eT[4][s];

        // tanh(x) = 1 - 2/(exp(2x)+1); saturates correctly at +/-inf.
        float a0 = __expf(1.f - 2.f / (__expf(2.f * (sw * e0 + b0)) + 1.f));
        float a1 = __expf(1.f - 2.f / (__expf(2.f * (sw * e1 + b1)) + 1.f));
        float a2 = __expf(1.f - 2.f / (__expf(2.f * (sw * e2 + b2)) + 1.f));
        float a3 = __expf(1.f - 2.f / (__expf(2.f * (sw * e3 + b3)) + 1.f));
        float a4 = __expf(1.f - 2.f / (__expf(2.f * (sw * e4 + b4)) + 1.f));

        float inv = 1.f / ((((a0 + a1) + (a2 + a3)) + a4) + EPS);

        eT[0][s] = e0 * (a0 * inv);
        eT[1][s] = e1 * (a1 * inv);
        eT[2][s] = e2 * (a2 * inv);
        eT[3][s] = e3 * (a3 * inv);
        eT[4][s] = e4 * (a4 * inv);
    }
    __syncthreads();

    // ---- coalesced stores: SoA -> AoS gather, float4 out
    floatx4* o4 = (floatx4*)out;
    #pragma unroll
    for (int k = 0; k < 5; ++k) {
        int f0 = 1024 * k + 4 * t;
        floatx4 v;
        #pragma unroll
        for (int m = 0; m < 4; ++m) {
            int f = f0 + m;
            v[m] = eT[f % 5][f / 5];
        }
        o4[blk * 1280 + (size_t)(k * 256 + t)] = v;
    }
}

extern "C" void kernel_launch(void* const* d_in, const int* in_sizes, int n_in,
                              void* d_out, int out_size, void* d_ws, size_t ws_size,
                              hipStream_t stream) {
    const float* dp = (const float*)d_in[0]; // (N,6)
    const float* ep = (const float*)d_in[1]; // (N,5)
    const float* Wp = (const float*)d_in[2]; // (1,)
    const float* bp = (const float*)d_in[3]; // (5,)
    float* out = (float*)d_out;              // (N,5)

    int N = in_sizes[1] / 5;   // e is N*5 elements
    int blocks = N / 1024;     // 4194304 / 1024 = 4096, exact
    attn_e_kernel<<<blocks, 256, 0, stream>>>(dp, ep, Wp, bp, out);
}

// Round 7
// 48.777 us; speedup vs baseline: 2.1910x; 1.2284x over previous
//
#include <hip/hip_runtime.h>

#define EPS 1e-7f

// Native clang vector type, component-indexed only with constants after
// full unroll (SROA-friendly: no address-taking of locals).
typedef float floatx4 __attribute__((ext_vector_type(4)));

// R1 structure (best so far, 49.2us): 4 consecutive samples per thread,
// all global accesses float4-aligned; d rows 4x6 = 6 float4, e rows
// 4x5 = 5 float4. Plain stores (nt stores caused 2.6x write amplification).
//
// Change vs R1: __launch_bounds__(256, 4) — min 4 waves/EU permits up to
// 128 VGPRs. R1 compiled to VGPR=32, which cannot hold the 11-float4 load
// burst (44 regs) in flight; the backend batched loads and stalled between
// batches (latency-bound: VALUBusy 16%, HBM 3.8/6.3 TB/s, occupancy 67%).
// Letting the allocator run to ~64-110 regs should cluster the full burst.
__global__ __launch_bounds__(256, 4) void attn_e_kernel(
    const float* __restrict__ dp, const float* __restrict__ ep,
    const float* __restrict__ Wp, const float* __restrict__ bp,
    float* __restrict__ out, int n4) // n4 = N/4
{
    int i = blockIdx.x * blockDim.x + threadIdx.x;
    if (i >= n4) return;

    float W = Wp[0];
    float bb[5];
    #pragma unroll
    for (int j = 0; j < 5; ++j) bb[j] = bp[j];

    const floatx4* d4 = (const floatx4*)dp;
    const floatx4* e4 = (const floatx4*)ep;

    floatx4 dv[6], ev[5], ov[5];
    #pragma unroll
    for (int k = 0; k < 6; ++k) dv[k] = d4[(size_t)i * 6 + k];
    #pragma unroll
    for (int k = 0; k < 5; ++k) ev[k] = e4[(size_t)i * 5 + k];

    #pragma unroll
    for (int r = 0; r < 4; ++r) {
        float s = 0.f;
        #pragma unroll
        for (int k = 0; k < 6; ++k) {
            int f = r * 6 + k;            // constant after unroll
            s += dv[f >> 2][f & 3];
        }
        float sw = s * W;

        float a[5];
        float asum = 0.f;
        #pragma unroll
        for (int j = 0; j < 5; ++j) {
            int f = r * 5 + j;
            float x = sw * ev[f >> 2][f & 3] + bb[j];
            // tanh(x) = 1 - 2/(exp(2x)+1); saturates correctly at +/-inf.
            float t = 1.f - 2.f / (__expf(2.f * x) + 1.f);
            float av = __expf(t);
            a[j] = av;
            asum += av;
        }
        float inv = 1.f / (asum + EPS);
        #pragma unroll
        for (int j = 0; j < 5; ++j) {
            int f = r * 5 + j;
            ov[f >> 2][f & 3] = ev[f >> 2][f & 3] * (a[j] * inv);
        }
    }

    floatx4* o4 = (floatx4*)out;
    #pragma unroll
    for (int k = 0; k < 5; ++k)
        o4[(size_t)i * 5 + k] = ov[k];
}

extern "C" void kernel_launch(void* const* d_in, const int* in_sizes, int n_in,
                              void* d_out, int out_size, void* d_ws, size_t ws_size,
                              hipStream_t stream) {
    const float* dp = (const float*)d_in[0]; // (N,6)
    const float* ep = (const float*)d_in[1]; // (N,5)
    const float* Wp = (const float*)d_in[2]; // (1,)
    const float* bp = (const float*)d_in[3]; // (5,)
    float* out = (float*)d_out;              // (N,5)

    int N = in_sizes[1] / 5; // e is N*5 elements
    int n4 = N / 4;          // N = 4194304 divisible by 4
    int threads = 256;
    int blocks = (n4 + threads - 1) / threads;
    attn_e_kernel<<<blocks, threads, 0, stream>>>(dp, ep, Wp, bp, out, n4);
}

// Round 8
// 46.635 us; speedup vs baseline: 2.2916x; 1.0459x over previous
//
#include <hip/hip_runtime.h>

#define EPS 1e-7f

// Native clang vector type, component-indexed only with constants after
// full unroll (SROA-friendly: no address-taking of locals).
typedef float floatx4 __attribute__((ext_vector_type(4)));

// Two distant 4-sample groups per thread (i and i+half). Each group keeps
// the proven dense layout (thread spans 96B of d / 80B of e -> wave region
// ~11KB, L1-resident; R5 showed contiguous-8 thrashes). All 22 float4
// loads are issued up front and pinned above a sched_barrier(0) so the
// backend cannot sink them to their uses (which kept VGPR=32 and MLP ~5
// loads/wave in R1/R7). Compute of group A overlaps group B's in-flight
// loads; plain stores (nt caused 2.6x write amplification in R4).
__global__ __launch_bounds__(256) void attn_e_kernel(
    const float* __restrict__ dp, const float* __restrict__ ep,
    const float* __restrict__ Wp, const float* __restrict__ bp,
    float* __restrict__ out, int half) // half = N/8 (thread count)
{
    int i = blockIdx.x * blockDim.x + threadIdx.x;
    if (i >= half) return;
    const size_t iA = i;
    const size_t iB = (size_t)i + (size_t)half;

    float W = Wp[0];
    float bb[5];
    #pragma unroll
    for (int j = 0; j < 5; ++j) bb[j] = bp[j];

    const floatx4* d4 = (const floatx4*)dp;
    const floatx4* e4 = (const floatx4*)ep;

    floatx4 dvA[6], evA[5], dvB[6], evB[5];
    #pragma unroll
    for (int k = 0; k < 6; ++k) dvA[k] = d4[iA * 6 + k];
    #pragma unroll
    for (int k = 0; k < 5; ++k) evA[k] = e4[iA * 5 + k];
    #pragma unroll
    for (int k = 0; k < 6; ++k) dvB[k] = d4[iB * 6 + k];
    #pragma unroll
    for (int k = 0; k < 5; ++k) evB[k] = e4[iB * 5 + k];

    // Pin: all 22 loads stay above, all compute below -> backend must hold
    // the full burst in registers (MLP 22/wave instead of ~5).
    __builtin_amdgcn_sched_barrier(0);

    floatx4* o4 = (floatx4*)out;

    #pragma unroll
    for (int g = 0; g < 2; ++g) {
        const floatx4* dv = g ? dvB : dvA;
        const floatx4* ev = g ? evB : evA;
        const size_t ii = g ? iB : iA;
        floatx4 ov[5];

        #pragma unroll
        for (int r = 0; r < 4; ++r) {
            float s = 0.f;
            #pragma unroll
            for (int k = 0; k < 6; ++k) {
                int f = r * 6 + k;            // constant after unroll
                s += dv[f >> 2][f & 3];
            }
            float sw = s * W;

            float a[5];
            float asum = 0.f;
            #pragma unroll
            for (int j = 0; j < 5; ++j) {
                int f = r * 5 + j;
                float x = sw * ev[f >> 2][f & 3] + bb[j];
                // tanh(x) = 1 - 2/(exp(2x)+1); saturates at +/-inf.
                float t = 1.f - 2.f / (__expf(2.f * x) + 1.f);
                float av = __expf(t);
                a[j] = av;
                asum += av;
            }
            float inv = 1.f / (asum + EPS);
            #pragma unroll
            for (int j = 0; j < 5; ++j) {
                int f = r * 5 + j;
                ov[f >> 2][f & 3] = ev[f >> 2][f & 3] * (a[j] * inv);
            }
        }

        #pragma unroll
        for (int k = 0; k < 5; ++k)
            o4[ii * 5 + k] = ov[k];
    }
}

extern "C" void kernel_launch(void* const* d_in, const int* in_sizes, int n_in,
                              void* d_out, int out_size, void* d_ws, size_t ws_size,
                              hipStream_t stream) {
    const float* dp = (const float*)d_in[0]; // (N,6)
    const float* ep = (const float*)d_in[1]; // (N,5)
    const float* Wp = (const float*)d_in[2]; // (1,)
    const float* bp = (const float*)d_in[3]; // (5,)
    float* out = (float*)d_out;              // (N,5)

    int N = in_sizes[1] / 5; // e is N*5 elements
    int half = N / 8;        // two 4-sample groups per thread
    int threads = 256;
    int blocks = (half + threads - 1) / threads;
    attn_e_kernel<<<blocks, threads, 0, stream>>>(dp, ep, Wp, bp, out, half);
}